// Round 12
// baseline (185.169 us; speedup 1.0000x reference)
//
#include <hip/hip_runtime.h>
#include <hip/hip_fp8.h>
#include <math.h>

typedef __attribute__((ext_vector_type(8))) short bf16x8;
typedef __attribute__((ext_vector_type(4))) float f32x4;

constexpr int kN   = 50000;
constexpr int kIn  = 128;
constexpr int kHid = 128;
constexpr int kOut = 40;
constexpr int kNT  = 16;              // dst nodes per block (8 waves x 2)
constexpr int kLds = 1032;            // ushort row stride of aggHi
constexpr float kBnEps = 1e-5f;

// Workspace layout (bytes):
//   [0, 262144)            W1hi
//   [262144, 360448)       W2hi  (no-z fallback)
//   [360448, 491520)       W2z   (128 frags x 1024B, 512 cols, bf16)
//   [524288, +12.8MB)      xb
//   [13324288, ...)        useZ: z8 (25.6M fp8);  else: h1b(12.8M)
constexpr size_t kOffW2hi = 262144;
constexpr size_t kOffW2z  = 360448;
constexpr size_t kOffXb   = 524288;
constexpr size_t kOffBig  = 13324288;
constexpr size_t kZBytes  = (size_t)kN * 512;            // 25,600,000 (fp8)

// bf16 helpers
__device__ inline float bf2f(ushort s) { return __uint_as_float(((uint)s) << 16); }

// pure-C RNE fp32->bf16 (no inline asm; compiler handles MFMA->VALU hazards)
__device__ __forceinline__ ushort f2bf(float x) {
    uint u = __float_as_uint(x);
    u += 0x7FFFu + ((u >> 16) & 1u);
    return (ushort)(u >> 16);
}

// v_cvt_pk_bf16_f32 — ONLY on compiler-VALU-produced inputs (proven paths).
__device__ __forceinline__ uint cvtpk(float a, float b) {
    uint r;
    asm("v_cvt_pk_bf16_f32 %0, %1, %2" : "=v"(r) : "v"(a), "v"(b));
    return r;
}

// fp8 e4m3 encode/decode via HIP type (OCP e4m3fn on gfx950)
__device__ __forceinline__ uchar f2fp8(float x) {
    __hip_fp8_e4m3 v(x);
    return *(uchar*)&v;
}
__device__ __forceinline__ float fp82f(uchar b) {
    __hip_fp8_e4m3 v;
    *(uchar*)&v = b;
    return (float)v;
}

#define RD(V, J) __builtin_amdgcn_readlane((V), (J))

// ---------------------------------------------------------------------------
// prep: (a) cast x->bf16  (b) pack W1  (c) pack W2hi  (d) pack W2z (512 cols)
// ---------------------------------------------------------------------------
__device__ __forceinline__ void pack_unit(const float* __restrict__ W,
                                          ushort* __restrict__ dst,
                                          int N, int frag, int lane)
{
    const int kt = frag & 31;
    const int nt = frag >> 5;
    const int n  = nt * 16 + (lane & 15);
    const int q  = lane >> 4;
    float f[8];
    #pragma unroll
    for (int j = 0; j < 8; ++j) {
        const int k = kt * 32 + q * 8 + j;
        f[j] = (n < N) ? W[(size_t)k * N + n] : 0.f;
    }
    const size_t o = ((size_t)frag * 64 + lane) * 8;
    *(uint4*)&dst[o] = make_uint4(cvtpk(f[0], f[1]), cvtpk(f[2], f[3]),
                                  cvtpk(f[4], f[5]), cvtpk(f[6], f[7]));
}

__global__ __launch_bounds__(256)
void prep(const float* __restrict__ x,  ushort* __restrict__ xb,
          const float* __restrict__ W1, ushort* __restrict__ W1hi,
          const float* __restrict__ W2, ushort* __restrict__ W2hi,
          ushort* __restrict__ W2z, int useZ)
{
    const int b   = blockIdx.x;
    const int tid = threadIdx.x;
    if (b < 3125) {
        const size_t i = ((size_t)b * 256 + tid) * 8;
        const float4 v0 = *(const float4*)&x[i];
        const float4 v1 = *(const float4*)&x[i + 4];
        *(uint4*)&xb[i] = make_uint4(cvtpk(v0.x, v0.y), cvtpk(v0.z, v0.w),
                                     cvtpk(v1.x, v1.y), cvtpk(v1.z, v1.w));
    } else if (b < 3125 + 64) {
        pack_unit(W1, W1hi, kHid, (b - 3125) * 4 + (tid >> 6), tid & 63);
    } else if (b < 3213) {
        const int frag = (b - 3189) * 4 + (tid >> 6);
        if (frag < 96) pack_unit(W2, W2hi, kOut, frag, tid & 63);
    } else if (useZ) {
        // W2z: 512 cols c = r*64 + o (o<40 real, else 0); K=128; KT=4.
        const int frag = (b - 3213) * 4 + (tid >> 6);     // 0..127
        const int kt   = frag & 3;
        const int nt   = frag >> 2;                       // 0..31
        const int lane = tid & 63;
        const int c    = nt * 16 + (lane & 15);
        const int r    = c >> 6;
        const int o    = c & 63;
        const int q    = lane >> 4;
        float f[8];
        #pragma unroll
        for (int j = 0; j < 8; ++j) {
            const int k = kt * 32 + q * 8 + j;
            f[j] = (o < kOut) ? W2[((size_t)r * kHid + k) * kOut + o] : 0.f;
        }
        const size_t of = ((size_t)frag * 64 + lane) * 8;
        *(uint4*)&W2z[of] = make_uint4(cvtpk(f[0], f[1]), cvtpk(f[2], f[3]),
                                       cvtpk(f[4], f[5]), cvtpk(f[6], f[7]));
    }
}

// ---------------------------------------------------------------------------
// Phase A (R6-proven): per-wave one-hot-MFMA aggregation, reg-staged, no asm.
// ---------------------------------------------------------------------------
__device__ __forceinline__ void stage_fast(const char* fb, int vi, char* msW,
                                           int hOff, int lane)
{
    const int b = (lane & 7) * 16;
    #pragma unroll
    for (int u = 0; u < 4; ++u) {
        const int e   = u * 8 + (lane >> 3);
        const int src = __shfl(vi, e, 64);
        const uint4 v = *(const uint4*)(fb + (((size_t)(uint)src) << 8) + hOff + b);
        *(uint4*)(msW + e * 128 + (b ^ (u << 5))) = v;   // u == (e>>3)&3
    }
}

__device__ __forceinline__ void stage_slow(const char* fb,
                                           const int* __restrict__ idx,
                                           int p0, int p1, int deg0, int deg1,
                                           char* msW, int hOff, int lane)
{
    const int l31 = lane & 31;
    if (lane < 32) {
        for (int e = 0; e < 32; ++e) {
            const bool eok = (e < 16) ? (e < deg0) : ((e - 16) < deg1);
            uint val = 0;
            if (eok) {
                const int g = (e < 16) ? (p0 + e) : (p1 + (e - 16));
                const int s = idx[g];
                val = *(const uint*)(fb + (((size_t)(uint)s) << 8) + hOff + l31 * 4);
            }
            *(uint*)(msW + e * 128 + ((l31 * 4) ^ (((e >> 3) & 3) << 5))) = val;
        }
    }
}

__device__ __forceinline__ bf16x8 readB(const char* msW, int q, int m, int ntL)
{
    const char* ap = msW + q * 1024 + 2 * m + (((ntL ^ q) & 3) << 5);
    bf16x8 b;
    #pragma unroll
    for (int j = 0; j < 8; ++j) b[j] = *(const short*)(ap + j * 128);
    return b;
}

__device__ __forceinline__ void mfma_store(bf16x8 aS, bf16x8 bb, int fbase,
                                           int ntL, int w, int q, int m,
                                           ushort (*aggHi)[kLds])
{
    f32x4 z = {0.f, 0.f, 0.f, 0.f};
    const f32x4 d = __builtin_amdgcn_mfma_f32_16x16x32_bf16(aS, bb, z, 0, 0, 0);
    ushort* dst = &aggHi[2 * w + (q >> 1)][0];
    const int fcol = fbase + ntL * 16 + m;
    const int rb   = (q & 1) * 4;
    dst[(rb + 0) * 128 + fcol] = f2bf(d[0]);
    dst[(rb + 1) * 128 + fcol] = f2bf(d[1]);
    dst[(rb + 2) * 128 + fcol] = f2bf(d[2]);
    dst[(rb + 3) * 128 + fcol] = f2bf(d[3]);
}

__device__ __forceinline__ void phaseA_mfma(const ushort* __restrict__ feat,
                                            const int* __restrict__ ptr,
                                            const int* __restrict__ idx,
                                            const int* __restrict__ etype,
                                            int base, ushort (*aggHi)[kLds],
                                            char* msgs)
{
    const int lane = threadIdx.x & 63;
    const int w    = threadIdx.x >> 6;            // 8 waves
    const int m    = lane & 15;
    const int q    = lane >> 4;
    const char* fb = (const char*)feat;

    const int node0 = base + 2 * w;
    const int p0 = ptr[node0];
    const int p1 = ptr[node0 + 1];
    const int p2 = ptr[node0 + 2];
    const int deg0 = p1 - p0, deg1 = p2 - p1;
    const bool fast = (deg0 == 16) && (deg1 == 16);

    const int vi = idx  [p0 + (lane & 31)];
    const int ve = etype[p0 + (lane & 31)];

    char* msW = msgs + w * 4096;

    int code;
    if (fast) {
        code = (((lane & 31) >> 4) << 3) | ve;
    } else {
        const int l31 = lane & 31;
        const bool eok = (l31 < 16) ? (l31 < deg0) : ((l31 - 16) < deg1);
        code = eok ? (((l31 >> 4) << 3) | ve) : 0xFF;
    }

    bf16x8 aS;
    #pragma unroll
    for (int j = 0; j < 8; ++j) {
        const int cj = __shfl(code, q * 8 + j, 64);
        aS[j] = (cj == m) ? (short)0x3F80 : (short)0;
    }

    if (fast) stage_fast(fb, vi, msW, 0, lane);
    else      stage_slow(fb, idx, p0, p1, deg0, deg1, msW, 0, lane);
    const bf16x8 b0 = readB(msW, q, m, 0);
    const bf16x8 b1 = readB(msW, q, m, 1);
    const bf16x8 b2 = readB(msW, q, m, 2);
    const bf16x8 b3 = readB(msW, q, m, 3);

    if (fast) stage_fast(fb, vi, msW, 128, lane);
    else      stage_slow(fb, idx, p0, p1, deg0, deg1, msW, 128, lane);

    mfma_store(aS, b0, 0, 0, w, q, m, aggHi);
    mfma_store(aS, b1, 0, 1, w, q, m, aggHi);
    mfma_store(aS, b2, 0, 2, w, q, m, aggHi);
    mfma_store(aS, b3, 0, 3, w, q, m, aggHi);

    const bf16x8 c0 = readB(msW, q, m, 0);
    const bf16x8 c1 = readB(msW, q, m, 1);
    const bf16x8 c2 = readB(msW, q, m, 2);
    const bf16x8 c3 = readB(msW, q, m, 3);
    mfma_store(aS, c0, 64, 0, w, q, m, aggHi);
    mfma_store(aS, c1, 64, 1, w, q, m, aggHi);
    mfma_store(aS, c2, 64, 2, w, q, m, aggHi);
    mfma_store(aS, c3, 64, 3, w, q, m, aggHi);
}

// ---------------------------------------------------------------------------
// Layer 1 (R11 fused form, proven 183.5 total): phase A + W1 GEMM + BN/ReLU,
// then z = h1 @ W2z via LDS mini-GEMM.  ONLY change vs R11: copyout converts
// z to fp8 e4m3 (64B per relation-slice -> one 64B granule per layer2z edge
// gather; table 51.2 -> 25.6MB).
// ---------------------------------------------------------------------------
__global__ __launch_bounds__(512, 4)
void rgcn_layer1(const ushort* __restrict__ xb,
                 const ushort* __restrict__ W1hi,
                 const ushort* __restrict__ W2z,
                 const float* __restrict__ gamma, const float* __restrict__ beta,
                 const float* __restrict__ mean,  const float* __restrict__ var,
                 const int* __restrict__ ptr, const int* __restrict__ idx,
                 const int* __restrict__ etype,
                 ushort* __restrict__ h1b, uchar* __restrict__ zbuf, int useZ)
{
    __shared__ ushort aggHi[kNT][kLds];              // 33,024 B
    __shared__ __align__(16) char msgs[8 * 4096];    // 32,768 B
    const int tid  = threadIdx.x;
    const int base = blockIdx.x * kNT;

    phaseA_mfma(xb, ptr, idx, etype, base, aggHi, msgs);
    __syncthreads();

    const int lane = tid & 63;
    const int wid  = tid >> 6;
    const int m    = lane & 15;
    const int q    = lane >> 4;

    const bf16x8* Bh = (const bf16x8*)W1hi + (size_t)wid * 32 * 64 + lane;
    f32x4 acc = {0.f, 0.f, 0.f, 0.f};

    #pragma unroll 4
    for (int kt = 0; kt < 32; ++kt) {
        const bf16x8 ah = *(const bf16x8*)&aggHi[m][kt * 32 + q * 8];
        const bf16x8 bh = Bh[(size_t)kt * 64];
        acc = __builtin_amdgcn_mfma_f32_16x16x32_bf16(ah, bh, acc, 0, 0, 0);
    }

    const int c = wid * 16 + m;
    const float g  = gamma[c] * rsqrtf(var[c] + kBnEps);
    const float mu = mean[c];
    const float bt = beta[c];
    float v[4];
    #pragma unroll
    for (int i = 0; i < 4; ++i) {
        const int node = base + q * 4 + i;
        const float invdeg = 1.0f / (float)(ptr[node + 1] - ptr[node]);
        v[i] = fmaxf((acc[i] * invdeg - mu) * g + bt, 0.f);
    }
    const uint p01 = cvtpk(v[0], v[1]);
    const uint p23 = cvtpk(v[2], v[3]);

    if (useZ) {
        // h1 tile -> LDS; zlds occupies [0,16768), h1lds at [16768,21120)
        ushort (*h1lds)[136] = (ushort (*)[136])(msgs + 16768);
        h1lds[q * 4 + 0][c] = (ushort)(p01 & 0xFFFFu);
        h1lds[q * 4 + 1][c] = (ushort)(p01 >> 16);
        h1lds[q * 4 + 2][c] = (ushort)(p23 & 0xFFFFu);
        h1lds[q * 4 + 3][c] = (ushort)(p23 >> 16);
        __syncthreads();

        ushort (*zlds)[524] = (ushort (*)[524])msgs;     // 524-stride: 2-way
        const bf16x8* B2 = (const bf16x8*)W2z;
        #pragma unroll
        for (int t = 0; t < 4; ++t) {
            const int nt = wid * 4 + t;
            f32x4 a2 = {0.f, 0.f, 0.f, 0.f};
            #pragma unroll
            for (int kt2 = 0; kt2 < 4; ++kt2) {
                const bf16x8 ah2 = *(const bf16x8*)&h1lds[m][kt2 * 32 + q * 8];
                const bf16x8 bh2 = B2[(size_t)(nt * 4 + kt2) * 64 + lane];
                a2 = __builtin_amdgcn_mfma_f32_16x16x32_bf16(ah2, bh2, a2, 0, 0, 0);
            }
            zlds[q * 4 + 0][nt * 16 + m] = f2bf(a2[0]);
            zlds[q * 4 + 1][nt * 16 + m] = f2bf(a2[1]);
            zlds[q * 4 + 2][nt * 16 + m] = f2bf(a2[2]);
            zlds[q * 4 + 3][nt * 16 + m] = f2bf(a2[3]);
        }
        __syncthreads();

        // copyout + fp8 encode: thread covers 16 cols of one row.
        // 512 thr x 16B = 8KB fp8 tile, fully coalesced.
        const int row = tid >> 5;
        const int cs  = (tid & 31) * 16;
        alignas(16) uchar ob[16];
        #pragma unroll
        for (int jj = 0; jj < 16; ++jj)
            ob[jj] = f2fp8(bf2f(zlds[row][cs + jj]));
        uchar* zp = zbuf + ((size_t)(base + row)) * 512 + cs;
        *(uint4*)zp = *(const uint4*)ob;
    } else {
        const int n0 = base + q * 4;
        h1b[(size_t)(n0 + 0) * kHid + c] = (ushort)(p01 & 0xFFFFu);
        h1b[(size_t)(n0 + 1) * kHid + c] = (ushort)(p01 >> 16);
        h1b[(size_t)(n0 + 2) * kHid + c] = (ushort)(p23 & 0xFFFFu);
        h1b[(size_t)(n0 + 3) * kHid + c] = (ushort)(p23 >> 16);
    }
}

// ---------------------------------------------------------------------------
// Layer 2 (no-z fallback, R6-verbatim)
// ---------------------------------------------------------------------------
__global__ __launch_bounds__(512, 4)
void rgcn_layer2(const ushort* __restrict__ h1b,
                 const ushort* __restrict__ W2hi,
                 const int* __restrict__ ptr, const int* __restrict__ idx,
                 const int* __restrict__ etype,
                 float* __restrict__ out)
{
    __shared__ ushort aggHi[kNT][kLds];
    __shared__ __align__(16) char msgs[8 * 4096];
    __shared__ float logits[kNT][48];
    const int tid  = threadIdx.x;
    const int base = blockIdx.x * kNT;

    phaseA_mfma(h1b, ptr, idx, etype, base, aggHi, msgs);
    __syncthreads();

    const int lane = tid & 63;
    const int wid  = tid >> 6;
    const int m    = lane & 15;
    const int q    = lane >> 4;

    if (wid < 3) {
        const bf16x8* Bh = (const bf16x8*)W2hi + (size_t)wid * 32 * 64 + lane;
        f32x4 acc = {0.f, 0.f, 0.f, 0.f};
        #pragma unroll 4
        for (int kt = 0; kt < 32; ++kt) {
            const bf16x8 ah = *(const bf16x8*)&aggHi[m][kt * 32 + q * 8];
            const bf16x8 bh = Bh[(size_t)kt * 64];
            acc = __builtin_amdgcn_mfma_f32_16x16x32_bf16(ah, bh, acc, 0, 0, 0);
        }
        const int n = wid * 16 + m;
        if (n < kOut) {
            #pragma unroll
            for (int i = 0; i < 4; ++i) {
                const int node = base + q * 4 + i;
                const float invdeg = 1.0f / (float)(ptr[node + 1] - ptr[node]);
                logits[q * 4 + i][n] = acc[i] * invdeg;
            }
        }
    }
    __syncthreads();

    #pragma unroll
    for (int i = 0; i < 2; ++i) {
        const int nrow = wid * 2 + i;
        const int node = base + nrow;
        const float v = (lane < kOut) ? logits[nrow][lane] : -INFINITY;
        float mx = v;
        #pragma unroll
        for (int off = 32; off > 0; off >>= 1)
            mx = fmaxf(mx, __shfl_xor(mx, off, 64));
        float s = (lane < kOut) ? __expf(v - mx) : 0.f;
        #pragma unroll
        for (int off = 32; off > 0; off >>= 1)
            s += __shfl_xor(s, off, 64);
        if (lane < kOut)
            out[(size_t)node * kOut + lane] = v - mx - __logf(s);
    }
}

// ---------------------------------------------------------------------------
// Layer 2z: out[i] = log_softmax( (sum_e z8[idx[e]][et[e]*64 + :]) / deg )
// fp8 gather: 64B (one granule) per edge.
// ---------------------------------------------------------------------------
__global__ __launch_bounds__(256)
void rgcn_layer2z(const uchar* __restrict__ z8,
                  const int* __restrict__ ptr, const int* __restrict__ idx,
                  const int* __restrict__ etype,
                  float* __restrict__ out)
{
    const int lane = threadIdx.x & 63;
    const int wv   = threadIdx.x >> 6;
    const int n0   = blockIdx.x * 16 + wv * 4;

    const int p0 = ptr[n0];
    const int d0 = ptr[n0 + 1] - p0;
    const int d1 = ptr[n0 + 2] - ptr[n0 + 1];
    const int d2 = ptr[n0 + 3] - ptr[n0 + 2];
    const int d3 = ptr[n0 + 4] - ptr[n0 + 3];
    const bool fast = (d0 == 16) & (d1 == 16) & (d2 == 16) & (d3 == 16);

    int vi = 0, ve = 0;
    if (fast) { vi = idx[p0 + lane]; ve = etype[p0 + lane]; }

    #pragma unroll
    for (int t = 0; t < 4; ++t) {
        const int node = n0 + t;
        float acc = 0.f;
        float invdeg;
        if (fast) {
            invdeg = 0.0625f;
            #pragma unroll
            for (int j = 0; j < 16; ++j) {
                const int e = t * 16 + j;
                const int s = RD(vi, e);
                const int r = RD(ve, e);
                acc += fp82f(z8[(size_t)(uint)s * 512 + (r << 6) + lane]);
            }
        } else {
            const int pa = ptr[node], pb = ptr[node + 1];
            invdeg = 1.0f / (float)(pb - pa);
            for (int e = pa; e < pb; ++e) {
                const int s = __builtin_amdgcn_readfirstlane(idx[e]);
                const int r = __builtin_amdgcn_readfirstlane(etype[e]);
                acc += fp82f(z8[(size_t)(uint)s * 512 + (r << 6) + lane]);
            }
        }
        const float v = (lane < kOut) ? acc * invdeg : -INFINITY;
        float mx = v;
        #pragma unroll
        for (int off = 32; off > 0; off >>= 1)
            mx = fmaxf(mx, __shfl_xor(mx, off, 64));
        float s2 = (lane < kOut) ? __expf(v - mx) : 0.f;
        #pragma unroll
        for (int off = 32; off > 0; off >>= 1)
            s2 += __shfl_xor(s2, off, 64);
        if (lane < kOut)
            out[(size_t)node * kOut + lane] = v - mx - __logf(s2);
    }
}

// ---------------------------------------------------------------------------
extern "C" void kernel_launch(void* const* d_in, const int* in_sizes, int n_in,
                              void* d_out, int out_size, void* d_ws, size_t ws_size,
                              hipStream_t stream)
{
    const float* x     = (const float*)d_in[0];
    const float* W1    = (const float*)d_in[1];
    const float* W2    = (const float*)d_in[2];
    const float* gamma = (const float*)d_in[3];
    const float* beta  = (const float*)d_in[4];
    const float* mean  = (const float*)d_in[5];
    const float* var   = (const float*)d_in[6];
    const int*   ptr   = (const int*)d_in[7];
    const int*   idx   = (const int*)d_in[8];
    const int*   et    = (const int*)d_in[9];
    float*       out   = (float*)d_out;

    char* ws = (char*)d_ws;
    ushort* W1hi = (ushort*)ws;
    ushort* W2hi = (ushort*)(ws + kOffW2hi);
    ushort* W2z  = (ushort*)(ws + kOffW2z);
    ushort* xb   = (ushort*)(ws + kOffXb);
    ushort* h1b  = (ushort*)(ws + kOffBig);      // fallback only
    uchar*  z8   = (uchar*)(ws + kOffBig);       // useZ path

    const int useZ = (ws_size >= kOffBig + kZBytes) ? 1 : 0;

    prep<<<dim3(3245), dim3(256), 0, stream>>>(x, xb, W1, W1hi, W2, W2hi,
                                               W2z, useZ);

    dim3 grid(kN / kNT), block(512);
    rgcn_layer1<<<grid, block, 0, stream>>>(xb, W1hi, W2z, gamma, beta, mean,
                                            var, ptr, idx, et, h1b, z8, useZ);
    if (useZ) {
        rgcn_layer2z<<<dim3(kN / 16), dim3(256), 0, stream>>>(z8, ptr, idx,
                                                              et, out);
    } else {
        rgcn_layer2<<<grid, block, 0, stream>>>(h1b, W2hi, ptr, idx, et, out);
    }
}

// Round 13
// 182.064 us; speedup vs baseline: 1.0171x; 1.0171x over previous
//
#include <hip/hip_runtime.h>
#include <hip/hip_fp8.h>
#include <math.h>

typedef __attribute__((ext_vector_type(8))) short bf16x8;
typedef __attribute__((ext_vector_type(4))) float f32x4;

constexpr int kN   = 50000;
constexpr int kIn  = 128;
constexpr int kHid = 128;
constexpr int kOut = 40;
constexpr int kNT  = 16;              // dst nodes per block (8 waves x 2)
constexpr int kLds = 1032;            // ushort row stride of aggHi
constexpr float kBnEps = 1e-5f;

// Workspace layout (bytes):
//   [0, 262144)            W1hi
//   [262144, 360448)       W2hi  (no-z fallback)
//   [360448, 491520)       W2z   (128 frags x 1024B, 512 cols, bf16)
//   [524288, +12.8MB)      xb
//   [13324288, ...)        useZ: z8 (25.6M fp8);  else: h1b(12.8M)
constexpr size_t kOffW2hi = 262144;
constexpr size_t kOffW2z  = 360448;
constexpr size_t kOffXb   = 524288;
constexpr size_t kOffBig  = 13324288;
constexpr size_t kZBytes  = (size_t)kN * 512;            // 25,600,000 (fp8)

// bf16 helpers
__device__ inline float bf2f(ushort s) { return __uint_as_float(((uint)s) << 16); }

// pure-C RNE fp32->bf16 (no inline asm; compiler handles MFMA->VALU hazards)
__device__ __forceinline__ ushort f2bf(float x) {
    uint u = __float_as_uint(x);
    u += 0x7FFFu + ((u >> 16) & 1u);
    return (ushort)(u >> 16);
}

// v_cvt_pk_bf16_f32 — ONLY on compiler-VALU-produced inputs (proven paths).
__device__ __forceinline__ uint cvtpk(float a, float b) {
    uint r;
    asm("v_cvt_pk_bf16_f32 %0, %1, %2" : "=v"(r) : "v"(a), "v"(b));
    return r;
}

// fp8 e4m3 encode/decode via HIP type (OCP e4m3fn on gfx950)
__device__ __forceinline__ uchar f2fp8(float x) {
    __hip_fp8_e4m3 v(x);
    return *(uchar*)&v;
}
__device__ __forceinline__ float fp82f(uchar b) {
    __hip_fp8_e4m3 v;
    *(uchar*)&v = b;
    return (float)v;
}

#define RD(V, J) __builtin_amdgcn_readlane((V), (J))

// ---------------------------------------------------------------------------
// prep: (a) cast x->bf16  (b) pack W1  (c) pack W2hi  (d) pack W2z (512 cols)
// ---------------------------------------------------------------------------
__device__ __forceinline__ void pack_unit(const float* __restrict__ W,
                                          ushort* __restrict__ dst,
                                          int N, int frag, int lane)
{
    const int kt = frag & 31;
    const int nt = frag >> 5;
    const int n  = nt * 16 + (lane & 15);
    const int q  = lane >> 4;
    float f[8];
    #pragma unroll
    for (int j = 0; j < 8; ++j) {
        const int k = kt * 32 + q * 8 + j;
        f[j] = (n < N) ? W[(size_t)k * N + n] : 0.f;
    }
    const size_t o = ((size_t)frag * 64 + lane) * 8;
    *(uint4*)&dst[o] = make_uint4(cvtpk(f[0], f[1]), cvtpk(f[2], f[3]),
                                  cvtpk(f[4], f[5]), cvtpk(f[6], f[7]));
}

__global__ __launch_bounds__(256)
void prep(const float* __restrict__ x,  ushort* __restrict__ xb,
          const float* __restrict__ W1, ushort* __restrict__ W1hi,
          const float* __restrict__ W2, ushort* __restrict__ W2hi,
          ushort* __restrict__ W2z, int useZ)
{
    const int b   = blockIdx.x;
    const int tid = threadIdx.x;
    if (b < 3125) {
        const size_t i = ((size_t)b * 256 + tid) * 8;
        const float4 v0 = *(const float4*)&x[i];
        const float4 v1 = *(const float4*)&x[i + 4];
        *(uint4*)&xb[i] = make_uint4(cvtpk(v0.x, v0.y), cvtpk(v0.z, v0.w),
                                     cvtpk(v1.x, v1.y), cvtpk(v1.z, v1.w));
    } else if (b < 3125 + 64) {
        pack_unit(W1, W1hi, kHid, (b - 3125) * 4 + (tid >> 6), tid & 63);
    } else if (b < 3213) {
        const int frag = (b - 3189) * 4 + (tid >> 6);
        if (frag < 96) pack_unit(W2, W2hi, kOut, frag, tid & 63);
    } else if (useZ) {
        // W2z: 512 cols c = r*64 + o (o<40 real, else 0); K=128; KT=4.
        const int frag = (b - 3213) * 4 + (tid >> 6);     // 0..127
        const int kt   = frag & 3;
        const int nt   = frag >> 2;                       // 0..31
        const int lane = tid & 63;
        const int c    = nt * 16 + (lane & 15);
        const int r    = c >> 6;
        const int o    = c & 63;
        const int q    = lane >> 4;
        float f[8];
        #pragma unroll
        for (int j = 0; j < 8; ++j) {
            const int k = kt * 32 + q * 8 + j;
            f[j] = (o < kOut) ? W2[((size_t)r * kHid + k) * kOut + o] : 0.f;
        }
        const size_t of = ((size_t)frag * 64 + lane) * 8;
        *(uint4*)&W2z[of] = make_uint4(cvtpk(f[0], f[1]), cvtpk(f[2], f[3]),
                                       cvtpk(f[4], f[5]), cvtpk(f[6], f[7]));
    }
}

// ---------------------------------------------------------------------------
// Phase A (R6-proven): per-wave one-hot-MFMA aggregation, reg-staged, no asm.
// ---------------------------------------------------------------------------
__device__ __forceinline__ void stage_fast(const char* fb, int vi, char* msW,
                                           int hOff, int lane)
{
    const int b = (lane & 7) * 16;
    #pragma unroll
    for (int u = 0; u < 4; ++u) {
        const int e   = u * 8 + (lane >> 3);
        const int src = __shfl(vi, e, 64);
        const uint4 v = *(const uint4*)(fb + (((size_t)(uint)src) << 8) + hOff + b);
        *(uint4*)(msW + e * 128 + (b ^ (u << 5))) = v;   // u == (e>>3)&3
    }
}

__device__ __forceinline__ void stage_slow(const char* fb,
                                           const int* __restrict__ idx,
                                           int p0, int p1, int deg0, int deg1,
                                           char* msW, int hOff, int lane)
{
    const int l31 = lane & 31;
    if (lane < 32) {
        for (int e = 0; e < 32; ++e) {
            const bool eok = (e < 16) ? (e < deg0) : ((e - 16) < deg1);
            uint val = 0;
            if (eok) {
                const int g = (e < 16) ? (p0 + e) : (p1 + (e - 16));
                const int s = idx[g];
                val = *(const uint*)(fb + (((size_t)(uint)s) << 8) + hOff + l31 * 4);
            }
            *(uint*)(msW + e * 128 + ((l31 * 4) ^ (((e >> 3) & 3) << 5))) = val;
        }
    }
}

__device__ __forceinline__ bf16x8 readB(const char* msW, int q, int m, int ntL)
{
    const char* ap = msW + q * 1024 + 2 * m + (((ntL ^ q) & 3) << 5);
    bf16x8 b;
    #pragma unroll
    for (int j = 0; j < 8; ++j) b[j] = *(const short*)(ap + j * 128);
    return b;
}

__device__ __forceinline__ void mfma_store(bf16x8 aS, bf16x8 bb, int fbase,
                                           int ntL, int w, int q, int m,
                                           ushort (*aggHi)[kLds])
{
    f32x4 z = {0.f, 0.f, 0.f, 0.f};
    const f32x4 d = __builtin_amdgcn_mfma_f32_16x16x32_bf16(aS, bb, z, 0, 0, 0);
    ushort* dst = &aggHi[2 * w + (q >> 1)][0];
    const int fcol = fbase + ntL * 16 + m;
    const int rb   = (q & 1) * 4;
    dst[(rb + 0) * 128 + fcol] = f2bf(d[0]);
    dst[(rb + 1) * 128 + fcol] = f2bf(d[1]);
    dst[(rb + 2) * 128 + fcol] = f2bf(d[2]);
    dst[(rb + 3) * 128 + fcol] = f2bf(d[3]);
}

__device__ __forceinline__ void phaseA_mfma(const ushort* __restrict__ feat,
                                            const int* __restrict__ ptr,
                                            const int* __restrict__ idx,
                                            const int* __restrict__ etype,
                                            int base, ushort (*aggHi)[kLds],
                                            char* msgs)
{
    const int lane = threadIdx.x & 63;
    const int w    = threadIdx.x >> 6;            // 8 waves
    const int m    = lane & 15;
    const int q    = lane >> 4;
    const char* fb = (const char*)feat;

    const int node0 = base + 2 * w;
    const int p0 = ptr[node0];
    const int p1 = ptr[node0 + 1];
    const int p2 = ptr[node0 + 2];
    const int deg0 = p1 - p0, deg1 = p2 - p1;
    const bool fast = (deg0 == 16) && (deg1 == 16);

    const int vi = idx  [p0 + (lane & 31)];
    const int ve = etype[p0 + (lane & 31)];

    char* msW = msgs + w * 4096;

    int code;
    if (fast) {
        code = (((lane & 31) >> 4) << 3) | ve;
    } else {
        const int l31 = lane & 31;
        const bool eok = (l31 < 16) ? (l31 < deg0) : ((l31 - 16) < deg1);
        code = eok ? (((l31 >> 4) << 3) | ve) : 0xFF;
    }

    bf16x8 aS;
    #pragma unroll
    for (int j = 0; j < 8; ++j) {
        const int cj = __shfl(code, q * 8 + j, 64);
        aS[j] = (cj == m) ? (short)0x3F80 : (short)0;
    }

    if (fast) stage_fast(fb, vi, msW, 0, lane);
    else      stage_slow(fb, idx, p0, p1, deg0, deg1, msW, 0, lane);
    const bf16x8 b0 = readB(msW, q, m, 0);
    const bf16x8 b1 = readB(msW, q, m, 1);
    const bf16x8 b2 = readB(msW, q, m, 2);
    const bf16x8 b3 = readB(msW, q, m, 3);

    if (fast) stage_fast(fb, vi, msW, 128, lane);
    else      stage_slow(fb, idx, p0, p1, deg0, deg1, msW, 128, lane);

    mfma_store(aS, b0, 0, 0, w, q, m, aggHi);
    mfma_store(aS, b1, 0, 1, w, q, m, aggHi);
    mfma_store(aS, b2, 0, 2, w, q, m, aggHi);
    mfma_store(aS, b3, 0, 3, w, q, m, aggHi);

    const bf16x8 c0 = readB(msW, q, m, 0);
    const bf16x8 c1 = readB(msW, q, m, 1);
    const bf16x8 c2 = readB(msW, q, m, 2);
    const bf16x8 c3 = readB(msW, q, m, 3);
    mfma_store(aS, c0, 64, 0, w, q, m, aggHi);
    mfma_store(aS, c1, 64, 1, w, q, m, aggHi);
    mfma_store(aS, c2, 64, 2, w, q, m, aggHi);
    mfma_store(aS, c3, 64, 3, w, q, m, aggHi);
}

// ---------------------------------------------------------------------------
// Layer 1 (R12 form, proven): phase A + W1 GEMM + BN/ReLU + fused z-GEMM,
// fp8 e4m3 copyout.  Unchanged this round.
// ---------------------------------------------------------------------------
__global__ __launch_bounds__(512, 4)
void rgcn_layer1(const ushort* __restrict__ xb,
                 const ushort* __restrict__ W1hi,
                 const ushort* __restrict__ W2z,
                 const float* __restrict__ gamma, const float* __restrict__ beta,
                 const float* __restrict__ mean,  const float* __restrict__ var,
                 const int* __restrict__ ptr, const int* __restrict__ idx,
                 const int* __restrict__ etype,
                 ushort* __restrict__ h1b, uchar* __restrict__ zbuf, int useZ)
{
    __shared__ ushort aggHi[kNT][kLds];              // 33,024 B
    __shared__ __align__(16) char msgs[8 * 4096];    // 32,768 B
    const int tid  = threadIdx.x;
    const int base = blockIdx.x * kNT;

    phaseA_mfma(xb, ptr, idx, etype, base, aggHi, msgs);
    __syncthreads();

    const int lane = tid & 63;
    const int wid  = tid >> 6;
    const int m    = lane & 15;
    const int q    = lane >> 4;

    const bf16x8* Bh = (const bf16x8*)W1hi + (size_t)wid * 32 * 64 + lane;
    f32x4 acc = {0.f, 0.f, 0.f, 0.f};

    #pragma unroll 4
    for (int kt = 0; kt < 32; ++kt) {
        const bf16x8 ah = *(const bf16x8*)&aggHi[m][kt * 32 + q * 8];
        const bf16x8 bh = Bh[(size_t)kt * 64];
        acc = __builtin_amdgcn_mfma_f32_16x16x32_bf16(ah, bh, acc, 0, 0, 0);
    }

    const int c = wid * 16 + m;
    const float g  = gamma[c] * rsqrtf(var[c] + kBnEps);
    const float mu = mean[c];
    const float bt = beta[c];
    float v[4];
    #pragma unroll
    for (int i = 0; i < 4; ++i) {
        const int node = base + q * 4 + i;
        const float invdeg = 1.0f / (float)(ptr[node + 1] - ptr[node]);
        v[i] = fmaxf((acc[i] * invdeg - mu) * g + bt, 0.f);
    }
    const uint p01 = cvtpk(v[0], v[1]);
    const uint p23 = cvtpk(v[2], v[3]);

    if (useZ) {
        // h1 tile -> LDS; zlds occupies [0,16768), h1lds at [16768,21120)
        ushort (*h1lds)[136] = (ushort (*)[136])(msgs + 16768);
        h1lds[q * 4 + 0][c] = (ushort)(p01 & 0xFFFFu);
        h1lds[q * 4 + 1][c] = (ushort)(p01 >> 16);
        h1lds[q * 4 + 2][c] = (ushort)(p23 & 0xFFFFu);
        h1lds[q * 4 + 3][c] = (ushort)(p23 >> 16);
        __syncthreads();

        ushort (*zlds)[524] = (ushort (*)[524])msgs;     // 524-stride: 2-way
        const bf16x8* B2 = (const bf16x8*)W2z;
        #pragma unroll
        for (int t = 0; t < 4; ++t) {
            const int nt = wid * 4 + t;
            f32x4 a2 = {0.f, 0.f, 0.f, 0.f};
            #pragma unroll
            for (int kt2 = 0; kt2 < 4; ++kt2) {
                const bf16x8 ah2 = *(const bf16x8*)&h1lds[m][kt2 * 32 + q * 8];
                const bf16x8 bh2 = B2[(size_t)(nt * 4 + kt2) * 64 + lane];
                a2 = __builtin_amdgcn_mfma_f32_16x16x32_bf16(ah2, bh2, a2, 0, 0, 0);
            }
            zlds[q * 4 + 0][nt * 16 + m] = f2bf(a2[0]);
            zlds[q * 4 + 1][nt * 16 + m] = f2bf(a2[1]);
            zlds[q * 4 + 2][nt * 16 + m] = f2bf(a2[2]);
            zlds[q * 4 + 3][nt * 16 + m] = f2bf(a2[3]);
        }
        __syncthreads();

        // copyout + fp8 encode: thread covers 16 cols of one row.
        const int row = tid >> 5;
        const int cs  = (tid & 31) * 16;
        alignas(16) uchar ob[16];
        #pragma unroll
        for (int jj = 0; jj < 16; ++jj)
            ob[jj] = f2fp8(bf2f(zlds[row][cs + jj]));
        uchar* zp = zbuf + ((size_t)(base + row)) * 512 + cs;
        *(uint4*)zp = *(const uint4*)ob;
    } else {
        const int n0 = base + q * 4;
        h1b[(size_t)(n0 + 0) * kHid + c] = (ushort)(p01 & 0xFFFFu);
        h1b[(size_t)(n0 + 1) * kHid + c] = (ushort)(p01 >> 16);
        h1b[(size_t)(n0 + 2) * kHid + c] = (ushort)(p23 & 0xFFFFu);
        h1b[(size_t)(n0 + 3) * kHid + c] = (ushort)(p23 >> 16);
    }
}

// ---------------------------------------------------------------------------
// Layer 2 (no-z fallback, R6-verbatim)
// ---------------------------------------------------------------------------
__global__ __launch_bounds__(512, 4)
void rgcn_layer2(const ushort* __restrict__ h1b,
                 const ushort* __restrict__ W2hi,
                 const int* __restrict__ ptr, const int* __restrict__ idx,
                 const int* __restrict__ etype,
                 float* __restrict__ out)
{
    __shared__ ushort aggHi[kNT][kLds];
    __shared__ __align__(16) char msgs[8 * 4096];
    __shared__ float logits[kNT][48];
    const int tid  = threadIdx.x;
    const int base = blockIdx.x * kNT;

    phaseA_mfma(h1b, ptr, idx, etype, base, aggHi, msgs);
    __syncthreads();

    const int lane = tid & 63;
    const int wid  = tid >> 6;
    const int m    = lane & 15;
    const int q    = lane >> 4;

    if (wid < 3) {
        const bf16x8* Bh = (const bf16x8*)W2hi + (size_t)wid * 32 * 64 + lane;
        f32x4 acc = {0.f, 0.f, 0.f, 0.f};
        #pragma unroll 4
        for (int kt = 0; kt < 32; ++kt) {
            const bf16x8 ah = *(const bf16x8*)&aggHi[m][kt * 32 + q * 8];
            const bf16x8 bh = Bh[(size_t)kt * 64];
            acc = __builtin_amdgcn_mfma_f32_16x16x32_bf16(ah, bh, acc, 0, 0, 0);
        }
        const int n = wid * 16 + m;
        if (n < kOut) {
            #pragma unroll
            for (int i = 0; i < 4; ++i) {
                const int node = base + q * 4 + i;
                const float invdeg = 1.0f / (float)(ptr[node + 1] - ptr[node]);
                logits[q * 4 + i][n] = acc[i] * invdeg;
            }
        }
    }
    __syncthreads();

    #pragma unroll
    for (int i = 0; i < 2; ++i) {
        const int nrow = wid * 2 + i;
        const int node = base + nrow;
        const float v = (lane < kOut) ? logits[nrow][lane] : -INFINITY;
        float mx = v;
        #pragma unroll
        for (int off = 32; off > 0; off >>= 1)
            mx = fmaxf(mx, __shfl_xor(mx, off, 64));
        float s = (lane < kOut) ? __expf(v - mx) : 0.f;
        #pragma unroll
        for (int off = 32; off > 0; off >>= 1)
            s += __shfl_xor(s, off, 64);
        if (lane < kOut)
            out[(size_t)node * kOut + lane] = v - mx - __logf(s);
    }
}

// ---------------------------------------------------------------------------
// Layer 2z (NEW): 16-lane group per node; one uint load per lane covers a
// full 64B edge slice per group -> 4 edges per wave-instruction.  Per wave:
// 16 load instructions for 4 nodes (was 64) -> 4x memory-level parallelism.
// No cross-group reduction: each group sums its own node's 16 edges.
// ---------------------------------------------------------------------------
__global__ __launch_bounds__(256)
void rgcn_layer2z(const uchar* __restrict__ z8,
                  const int* __restrict__ ptr, const int* __restrict__ idx,
                  const int* __restrict__ etype,
                  float* __restrict__ out)
{
    const int lane = threadIdx.x & 63;
    const int wv   = threadIdx.x >> 6;            // 4 waves/block
    const int n0   = blockIdx.x * 16 + wv * 4;    // wave covers nodes n0..n0+3
    const int g    = lane >> 4;                   // 16-lane group = local node
    const int c4   = (lane & 15) * 4;             // col base (4 cols per lane)
    const int node = n0 + g;

    const int p0 = ptr[n0];
    const int d0 = ptr[n0 + 1] - p0;
    const int d1 = ptr[n0 + 2] - ptr[n0 + 1];
    const int d2 = ptr[n0 + 3] - ptr[n0 + 2];
    const int d3 = ptr[n0 + 4] - ptr[n0 + 3];
    const bool fast = (d0 == 16) & (d1 == 16) & (d2 == 16) & (d3 == 16);

    float a0 = 0.f, a1 = 0.f, a2 = 0.f, a3 = 0.f;
    float invdeg;

    if (fast) {
        invdeg = 0.0625f;
        const int vi = idx  [p0 + lane];          // 64 edges, lane = edge slot
        const int ve = etype[p0 + lane];
        #pragma unroll
        for (int j = 0; j < 16; ++j) {
            const int E = g * 16 + j;             // this group's j-th edge
            const int s = __shfl(vi, E, 64);
            const int r = __shfl(ve, E, 64);
            const uint off = (uint)s * 512u + ((uint)r << 6) + (uint)c4;
            const uint v = *(const uint*)(z8 + off);
            a0 += fp82f((uchar)(v));
            a1 += fp82f((uchar)(v >> 8));
            a2 += fp82f((uchar)(v >> 16));
            a3 += fp82f((uchar)(v >> 24));
        }
    } else {                                      // generic (never hit)
        const int pa = ptr[node], pb = ptr[node + 1];
        invdeg = 1.0f / (float)(pb - pa);
        for (int e = pa; e < pb; ++e) {
            const int s = idx[e];
            const int r = etype[e];
            const uint off = (uint)s * 512u + ((uint)r << 6) + (uint)c4;
            const uint v = *(const uint*)(z8 + off);
            a0 += fp82f((uchar)(v));
            a1 += fp82f((uchar)(v >> 8));
            a2 += fp82f((uchar)(v >> 16));
            a3 += fp82f((uchar)(v >> 24));
        }
    }

    // softmax within the 16-lane group (lane&15 covers cols c4..c4+3)
    const bool valid = (lane & 15) < 10;          // c4+3 < 40
    const float v0 = a0 * invdeg, v1 = a1 * invdeg;
    const float v2 = a2 * invdeg, v3 = a3 * invdeg;
    float mx = valid ? fmaxf(fmaxf(v0, v1), fmaxf(v2, v3)) : -INFINITY;
    #pragma unroll
    for (int off = 8; off > 0; off >>= 1)
        mx = fmaxf(mx, __shfl_xor(mx, off, 64));
    float sm = valid ? (__expf(v0 - mx) + __expf(v1 - mx) +
                        __expf(v2 - mx) + __expf(v3 - mx)) : 0.f;
    #pragma unroll
    for (int off = 8; off > 0; off >>= 1)
        sm += __shfl_xor(sm, off, 64);
    if (valid) {
        const float lg = mx + __logf(sm);
        const float4 o4 = make_float4(v0 - lg, v1 - lg, v2 - lg, v3 - lg);
        *(float4*)&out[(size_t)node * kOut + c4] = o4;
    }
}

// ---------------------------------------------------------------------------
extern "C" void kernel_launch(void* const* d_in, const int* in_sizes, int n_in,
                              void* d_out, int out_size, void* d_ws, size_t ws_size,
                              hipStream_t stream)
{
    const float* x     = (const float*)d_in[0];
    const float* W1    = (const float*)d_in[1];
    const float* W2    = (const float*)d_in[2];
    const float* gamma = (const float*)d_in[3];
    const float* beta  = (const float*)d_in[4];
    const float* mean  = (const float*)d_in[5];
    const float* var   = (const float*)d_in[6];
    const int*   ptr   = (const int*)d_in[7];
    const int*   idx   = (const int*)d_in[8];
    const int*   et    = (const int*)d_in[9];
    float*       out   = (float*)d_out;

    char* ws = (char*)d_ws;
    ushort* W1hi = (ushort*)ws;
    ushort* W2hi = (ushort*)(ws + kOffW2hi);
    ushort* W2z  = (ushort*)(ws + kOffW2z);
    ushort* xb   = (ushort*)(ws + kOffXb);
    ushort* h1b  = (ushort*)(ws + kOffBig);      // fallback only
    uchar*  z8   = (uchar*)(ws + kOffBig);       // useZ path

    const int useZ = (ws_size >= kOffBig + kZBytes) ? 1 : 0;

    prep<<<dim3(3245), dim3(256), 0, stream>>>(x, xb, W1, W1hi, W2, W2hi,
                                               W2z, useZ);

    dim3 grid(kN / kNT), block(512);
    rgcn_layer1<<<grid, block, 0, stream>>>(xb, W1hi, W2z, gamma, beta, mean,
                                            var, ptr, idx, et, h1b, z8, useZ);
    if (useZ) {
        rgcn_layer2z<<<dim3(kN / 16), dim3(256), 0, stream>>>(z8, ptr, idx,
                                                              et, out);
    } else {
        rgcn_layer2<<<grid, block, 0, stream>>>(h1b, W2hi, ptr, idx, et, out);
    }
}

// Round 14
// 177.029 us; speedup vs baseline: 1.0460x; 1.0284x over previous
//
#include <hip/hip_runtime.h>
#include <hip/hip_fp8.h>
#include <math.h>

typedef __attribute__((ext_vector_type(8))) short bf16x8;
typedef __attribute__((ext_vector_type(4))) float f32x4;

constexpr int kN   = 50000;
constexpr int kIn  = 128;
constexpr int kHid = 128;
constexpr int kOut = 40;
constexpr int kNT  = 16;              // dst nodes per block (8 waves x 2)
constexpr int kLds = 1032;            // ushort row stride of aggHi
constexpr float kBnEps = 1e-5f;

// Workspace layout (bytes):
//   [0, 262144)            W1hi
//   [262144, 360448)       W2hi  (no-z fallback)
//   [360448, 491520)       W2z   (128 frags x 1024B, 512 cols, bf16)
//   [524288, +12.8MB)      xb (bf16, fallback) or xb8 (fp8, useZ; 6.4MB)
//   [13324288, ...)        useZ: z8 (25.6M fp8);  else: h1b(12.8M)
constexpr size_t kOffW2hi = 262144;
constexpr size_t kOffW2z  = 360448;
constexpr size_t kOffXb   = 524288;
constexpr size_t kOffBig  = 13324288;
constexpr size_t kZBytes  = (size_t)kN * 512;            // 25,600,000 (fp8)

// bf16 helpers
__device__ inline float bf2f(ushort s) { return __uint_as_float(((uint)s) << 16); }

// pure-C RNE fp32->bf16 (no inline asm; compiler handles MFMA->VALU hazards)
__device__ __forceinline__ ushort f2bf(float x) {
    uint u = __float_as_uint(x);
    u += 0x7FFFu + ((u >> 16) & 1u);
    return (ushort)(u >> 16);
}

// v_cvt_pk_bf16_f32 — ONLY on compiler-VALU-produced inputs (proven paths).
__device__ __forceinline__ uint cvtpk(float a, float b) {
    uint r;
    asm("v_cvt_pk_bf16_f32 %0, %1, %2" : "=v"(r) : "v"(a), "v"(b));
    return r;
}

// fp8 e4m3 encode/decode via HIP type (OCP e4m3fn on gfx950)
__device__ __forceinline__ uchar f2fp8(float x) {
    __hip_fp8_e4m3 v(x);
    return *(uchar*)&v;
}
__device__ __forceinline__ float fp82f(uchar b) {
    __hip_fp8_e4m3 v;
    *(uchar*)&v = b;
    return (float)v;
}

#define RD(V, J) __builtin_amdgcn_readlane((V), (J))

// ---------------------------------------------------------------------------
// prep: (a) cast x->fp8 (useZ) / bf16 (fallback)
//       (b) pack W1  (c) pack W2hi  (d) pack W2z (512 cols)
// ---------------------------------------------------------------------------
__device__ __forceinline__ void pack_unit(const float* __restrict__ W,
                                          ushort* __restrict__ dst,
                                          int N, int frag, int lane)
{
    const int kt = frag & 31;
    const int nt = frag >> 5;
    const int n  = nt * 16 + (lane & 15);
    const int q  = lane >> 4;
    float f[8];
    #pragma unroll
    for (int j = 0; j < 8; ++j) {
        const int k = kt * 32 + q * 8 + j;
        f[j] = (n < N) ? W[(size_t)k * N + n] : 0.f;
    }
    const size_t o = ((size_t)frag * 64 + lane) * 8;
    *(uint4*)&dst[o] = make_uint4(cvtpk(f[0], f[1]), cvtpk(f[2], f[3]),
                                  cvtpk(f[4], f[5]), cvtpk(f[6], f[7]));
}

__global__ __launch_bounds__(256)
void prep(const float* __restrict__ x,  ushort* __restrict__ xb,
          const float* __restrict__ W1, ushort* __restrict__ W1hi,
          const float* __restrict__ W2, ushort* __restrict__ W2hi,
          ushort* __restrict__ W2z, int useZ)
{
    const int b   = blockIdx.x;
    const int tid = threadIdx.x;
    if (b < 3125) {
        const size_t i = ((size_t)b * 256 + tid) * 8;
        const float4 v0 = *(const float4*)&x[i];
        const float4 v1 = *(const float4*)&x[i + 4];
        if (useZ) {
            // fp8 x table: 8 bytes per thread
            alignas(8) uchar ob[8] = {
                f2fp8(v0.x), f2fp8(v0.y), f2fp8(v0.z), f2fp8(v0.w),
                f2fp8(v1.x), f2fp8(v1.y), f2fp8(v1.z), f2fp8(v1.w)
            };
            *(uint2*)((uchar*)xb + i) = *(const uint2*)ob;
        } else {
            *(uint4*)&xb[i] = make_uint4(cvtpk(v0.x, v0.y), cvtpk(v0.z, v0.w),
                                         cvtpk(v1.x, v1.y), cvtpk(v1.z, v1.w));
        }
    } else if (b < 3125 + 64) {
        pack_unit(W1, W1hi, kHid, (b - 3125) * 4 + (tid >> 6), tid & 63);
    } else if (b < 3213) {
        const int frag = (b - 3189) * 4 + (tid >> 6);
        if (frag < 96) pack_unit(W2, W2hi, kOut, frag, tid & 63);
    } else if (useZ) {
        // W2z: 512 cols c = r*64 + o (o<40 real, else 0); K=128; KT=4.
        const int frag = (b - 3213) * 4 + (tid >> 6);     // 0..127
        const int kt   = frag & 3;
        const int nt   = frag >> 2;                       // 0..31
        const int lane = tid & 63;
        const int c    = nt * 16 + (lane & 15);
        const int r    = c >> 6;
        const int o    = c & 63;
        const int q    = lane >> 4;
        float f[8];
        #pragma unroll
        for (int j = 0; j < 8; ++j) {
            const int k = kt * 32 + q * 8 + j;
            f[j] = (o < kOut) ? W2[((size_t)r * kHid + k) * kOut + o] : 0.f;
        }
        const size_t of = ((size_t)frag * 64 + lane) * 8;
        *(uint4*)&W2z[of] = make_uint4(cvtpk(f[0], f[1]), cvtpk(f[2], f[3]),
                                       cvtpk(f[4], f[5]), cvtpk(f[6], f[7]));
    }
}

// ---------------------------------------------------------------------------
// Phase A (R6-proven structure): per-wave one-hot-MFMA aggregation.
// bf16 staging (fallback path) and fp8 staging (useZ path) produce an
// IDENTICAL swizzled bf16 LDS layout; readB / one-hot / MFMA are shared.
// ---------------------------------------------------------------------------
__device__ __forceinline__ void stage_fast(const char* fb, int vi, char* msW,
                                           int hOff, int lane)
{
    const int b = (lane & 7) * 16;
    #pragma unroll
    for (int u = 0; u < 4; ++u) {
        const int e   = u * 8 + (lane >> 3);
        const int src = __shfl(vi, e, 64);
        const uint4 v = *(const uint4*)(fb + (((size_t)(uint)src) << 8) + hOff + b);
        *(uint4*)(msW + e * 128 + (b ^ (u << 5))) = v;   // u == (e>>3)&3
    }
}

// fp8 fast staging: half-row = 64B; 32 edges x 4 chunks(16B fp8 = 32B bf16)
// = 128 tasks over 2 iterations.  LDS chunk c of edge e lands at
// e*128 + ((c ^ ((e>>3)&3)) * 32)  — byte-identical layout to stage_fast.
__device__ __forceinline__ void stage_fast_fp8(const char* fb8, int vi,
                                               char* msW, int hOff8, int lane)
{
    #pragma unroll
    for (int u = 0; u < 2; ++u) {
        const int t = u * 64 + lane;
        const int e = t >> 2;
        const int c = t & 3;
        const int src = __shfl(vi, e, 64);
        const uint4 v = *(const uint4*)(fb8 + (size_t)(uint)src * 128 + hOff8 + c * 16);
        const uint vv[4] = {v.x, v.y, v.z, v.w};
        uint w[8];
        #pragma unroll
        for (int k = 0; k < 4; ++k) {
            const uint bts = vv[k];
            w[k * 2 + 0] = cvtpk(fp82f((uchar)bts),         fp82f((uchar)(bts >> 8)));
            w[k * 2 + 1] = cvtpk(fp82f((uchar)(bts >> 16)), fp82f((uchar)(bts >> 24)));
        }
        char* lp = msW + e * 128 + ((c ^ ((e >> 3) & 3)) * 32);
        *(uint4*)lp        = make_uint4(w[0], w[1], w[2], w[3]);
        *(uint4*)(lp + 16) = make_uint4(w[4], w[5], w[6], w[7]);
    }
}

__device__ __forceinline__ void stage_slow(const char* fb,
                                           const int* __restrict__ idx,
                                           int p0, int p1, int deg0, int deg1,
                                           char* msW, int hOff, int lane)
{
    const int l31 = lane & 31;
    if (lane < 32) {
        for (int e = 0; e < 32; ++e) {
            const bool eok = (e < 16) ? (e < deg0) : ((e - 16) < deg1);
            uint val = 0;
            if (eok) {
                const int g = (e < 16) ? (p0 + e) : (p1 + (e - 16));
                const int s = idx[g];
                val = *(const uint*)(fb + (((size_t)(uint)s) << 8) + hOff + l31 * 4);
            }
            *(uint*)(msW + e * 128 + ((l31 * 4) ^ (((e >> 3) & 3) << 5))) = val;
        }
    }
}

__device__ __forceinline__ void stage_slow_fp8(const char* fb8,
                                               const int* __restrict__ idx,
                                               int p0, int p1, int deg0, int deg1,
                                               char* msW, int hOff8, int lane)
{
    const int l31 = lane & 31;
    if (lane < 32) {
        for (int e = 0; e < 32; ++e) {
            const bool eok = (e < 16) ? (e < deg0) : ((e - 16) < deg1);
            uint val = 0;
            if (eok) {
                const int g = (e < 16) ? (p0 + e) : (p1 + (e - 16));
                const int s = idx[g];
                const ushort two = *(const ushort*)(fb8 + (size_t)(uint)s * 128
                                                   + hOff8 + l31 * 2);
                val = cvtpk(fp82f((uchar)two), fp82f((uchar)(two >> 8)));
            }
            *(uint*)(msW + e * 128 + ((l31 * 4) ^ (((e >> 3) & 3) << 5))) = val;
        }
    }
}

__device__ __forceinline__ bf16x8 readB(const char* msW, int q, int m, int ntL)
{
    const char* ap = msW + q * 1024 + 2 * m + (((ntL ^ q) & 3) << 5);
    bf16x8 b;
    #pragma unroll
    for (int j = 0; j < 8; ++j) b[j] = *(const short*)(ap + j * 128);
    return b;
}

__device__ __forceinline__ void mfma_store(bf16x8 aS, bf16x8 bb, int fbase,
                                           int ntL, int w, int q, int m,
                                           ushort (*aggHi)[kLds])
{
    f32x4 z = {0.f, 0.f, 0.f, 0.f};
    const f32x4 d = __builtin_amdgcn_mfma_f32_16x16x32_bf16(aS, bb, z, 0, 0, 0);
    ushort* dst = &aggHi[2 * w + (q >> 1)][0];
    const int fcol = fbase + ntL * 16 + m;
    const int rb   = (q & 1) * 4;
    dst[(rb + 0) * 128 + fcol] = f2bf(d[0]);
    dst[(rb + 1) * 128 + fcol] = f2bf(d[1]);
    dst[(rb + 2) * 128 + fcol] = f2bf(d[2]);
    dst[(rb + 3) * 128 + fcol] = f2bf(d[3]);
}

// FP8 = 1: feat is a 128B/row fp8 table; FP8 = 0: 256B/row bf16 table.
template <int FP8>
__device__ __forceinline__ void phaseA_mfma(const void* __restrict__ feat,
                                            const int* __restrict__ ptr,
                                            const int* __restrict__ idx,
                                            const int* __restrict__ etype,
                                            int base, ushort (*aggHi)[kLds],
                                            char* msgs)
{
    const int lane = threadIdx.x & 63;
    const int w    = threadIdx.x >> 6;            // 8 waves
    const int m    = lane & 15;
    const int q    = lane >> 4;
    const char* fb = (const char*)feat;

    const int node0 = base + 2 * w;
    const int p0 = ptr[node0];
    const int p1 = ptr[node0 + 1];
    const int p2 = ptr[node0 + 2];
    const int deg0 = p1 - p0, deg1 = p2 - p1;
    const bool fast = (deg0 == 16) && (deg1 == 16);

    const int vi = idx  [p0 + (lane & 31)];
    const int ve = etype[p0 + (lane & 31)];

    char* msW = msgs + w * 4096;

    int code;
    if (fast) {
        code = (((lane & 31) >> 4) << 3) | ve;
    } else {
        const int l31 = lane & 31;
        const bool eok = (l31 < 16) ? (l31 < deg0) : ((l31 - 16) < deg1);
        code = eok ? (((l31 >> 4) << 3) | ve) : 0xFF;
    }

    bf16x8 aS;
    #pragma unroll
    for (int j = 0; j < 8; ++j) {
        const int cj = __shfl(code, q * 8 + j, 64);
        aS[j] = (cj == m) ? (short)0x3F80 : (short)0;
    }

    // ---- half 0
    if (FP8) {
        if (fast) stage_fast_fp8(fb, vi, msW, 0, lane);
        else      stage_slow_fp8(fb, idx, p0, p1, deg0, deg1, msW, 0, lane);
    } else {
        if (fast) stage_fast(fb, vi, msW, 0, lane);
        else      stage_slow(fb, idx, p0, p1, deg0, deg1, msW, 0, lane);
    }
    const bf16x8 b0 = readB(msW, q, m, 0);
    const bf16x8 b1 = readB(msW, q, m, 1);
    const bf16x8 b2 = readB(msW, q, m, 2);
    const bf16x8 b3 = readB(msW, q, m, 3);

    // ---- half 1 staging overlaps half-0 MFMAs (same-wave DS ordering)
    if (FP8) {
        if (fast) stage_fast_fp8(fb, vi, msW, 64, lane);
        else      stage_slow_fp8(fb, idx, p0, p1, deg0, deg1, msW, 64, lane);
    } else {
        if (fast) stage_fast(fb, vi, msW, 128, lane);
        else      stage_slow(fb, idx, p0, p1, deg0, deg1, msW, 128, lane);
    }

    mfma_store(aS, b0, 0, 0, w, q, m, aggHi);
    mfma_store(aS, b1, 0, 1, w, q, m, aggHi);
    mfma_store(aS, b2, 0, 2, w, q, m, aggHi);
    mfma_store(aS, b3, 0, 3, w, q, m, aggHi);

    const bf16x8 c0 = readB(msW, q, m, 0);
    const bf16x8 c1 = readB(msW, q, m, 1);
    const bf16x8 c2 = readB(msW, q, m, 2);
    const bf16x8 c3 = readB(msW, q, m, 3);
    mfma_store(aS, c0, 64, 0, w, q, m, aggHi);
    mfma_store(aS, c1, 64, 1, w, q, m, aggHi);
    mfma_store(aS, c2, 64, 2, w, q, m, aggHi);
    mfma_store(aS, c3, 64, 3, w, q, m, aggHi);
}

// ---------------------------------------------------------------------------
// Layer 1: phase A (fp8 x when useZ) + W1 GEMM + BN/ReLU + fused z-GEMM,
// fp8 e4m3 z copyout.  Identical to R13 except the FP8 phase-A staging.
// ---------------------------------------------------------------------------
__global__ __launch_bounds__(512, 4)
void rgcn_layer1(const void* __restrict__ xany,
                 const ushort* __restrict__ W1hi,
                 const ushort* __restrict__ W2z,
                 const float* __restrict__ gamma, const float* __restrict__ beta,
                 const float* __restrict__ mean,  const float* __restrict__ var,
                 const int* __restrict__ ptr, const int* __restrict__ idx,
                 const int* __restrict__ etype,
                 ushort* __restrict__ h1b, uchar* __restrict__ zbuf, int useZ)
{
    __shared__ ushort aggHi[kNT][kLds];              // 33,024 B
    __shared__ __align__(16) char msgs[8 * 4096];    // 32,768 B
    const int tid  = threadIdx.x;
    const int base = blockIdx.x * kNT;

    if (useZ) phaseA_mfma<1>(xany, ptr, idx, etype, base, aggHi, msgs);
    else      phaseA_mfma<0>(xany, ptr, idx, etype, base, aggHi, msgs);
    __syncthreads();

    const int lane = tid & 63;
    const int wid  = tid >> 6;
    const int m    = lane & 15;
    const int q    = lane >> 4;

    const bf16x8* Bh = (const bf16x8*)W1hi + (size_t)wid * 32 * 64 + lane;
    f32x4 acc = {0.f, 0.f, 0.f, 0.f};

    #pragma unroll 4
    for (int kt = 0; kt < 32; ++kt) {
        const bf16x8 ah = *(const bf16x8*)&aggHi[m][kt * 32 + q * 8];
        const bf16x8 bh = Bh[(size_t)kt * 64];
        acc = __builtin_amdgcn_mfma_f32_16x16x32_bf16(ah, bh, acc, 0, 0, 0);
    }

    const int c = wid * 16 + m;
    const float g  = gamma[c] * rsqrtf(var[c] + kBnEps);
    const float mu = mean[c];
    const float bt = beta[c];
    float v[4];
    #pragma unroll
    for (int i = 0; i < 4; ++i) {
        const int node = base + q * 4 + i;
        const float invdeg = 1.0f / (float)(ptr[node + 1] - ptr[node]);
        v[i] = fmaxf((acc[i] * invdeg - mu) * g + bt, 0.f);
    }
    const uint p01 = cvtpk(v[0], v[1]);
    const uint p23 = cvtpk(v[2], v[3]);

    if (useZ) {
        // h1 tile -> LDS; zlds occupies [0,16768), h1lds at [16768,21120)
        ushort (*h1lds)[136] = (ushort (*)[136])(msgs + 16768);
        h1lds[q * 4 + 0][c] = (ushort)(p01 & 0xFFFFu);
        h1lds[q * 4 + 1][c] = (ushort)(p01 >> 16);
        h1lds[q * 4 + 2][c] = (ushort)(p23 & 0xFFFFu);
        h1lds[q * 4 + 3][c] = (ushort)(p23 >> 16);
        __syncthreads();

        ushort (*zlds)[524] = (ushort (*)[524])msgs;     // 524-stride: 2-way
        const bf16x8* B2 = (const bf16x8*)W2z;
        #pragma unroll
        for (int t = 0; t < 4; ++t) {
            const int nt = wid * 4 + t;
            f32x4 a2 = {0.f, 0.f, 0.f, 0.f};
            #pragma unroll
            for (int kt2 = 0; kt2 < 4; ++kt2) {
                const bf16x8 ah2 = *(const bf16x8*)&h1lds[m][kt2 * 32 + q * 8];
                const bf16x8 bh2 = B2[(size_t)(nt * 4 + kt2) * 64 + lane];
                a2 = __builtin_amdgcn_mfma_f32_16x16x32_bf16(ah2, bh2, a2, 0, 0, 0);
            }
            zlds[q * 4 + 0][nt * 16 + m] = f2bf(a2[0]);
            zlds[q * 4 + 1][nt * 16 + m] = f2bf(a2[1]);
            zlds[q * 4 + 2][nt * 16 + m] = f2bf(a2[2]);
            zlds[q * 4 + 3][nt * 16 + m] = f2bf(a2[3]);
        }
        __syncthreads();

        // copyout + fp8 encode: thread covers 16 cols of one row.
        const int row = tid >> 5;
        const int cs  = (tid & 31) * 16;
        alignas(16) uchar ob[16];
        #pragma unroll
        for (int jj = 0; jj < 16; ++jj)
            ob[jj] = f2fp8(bf2f(zlds[row][cs + jj]));
        uchar* zp = zbuf + ((size_t)(base + row)) * 512 + cs;
        *(uint4*)zp = *(const uint4*)ob;
    } else {
        const int n0 = base + q * 4;
        h1b[(size_t)(n0 + 0) * kHid + c] = (ushort)(p01 & 0xFFFFu);
        h1b[(size_t)(n0 + 1) * kHid + c] = (ushort)(p01 >> 16);
        h1b[(size_t)(n0 + 2) * kHid + c] = (ushort)(p23 & 0xFFFFu);
        h1b[(size_t)(n0 + 3) * kHid + c] = (ushort)(p23 >> 16);
    }
}

// ---------------------------------------------------------------------------
// Layer 2 (no-z fallback, R6-verbatim; bf16 phase A on h1b)
// ---------------------------------------------------------------------------
__global__ __launch_bounds__(512, 4)
void rgcn_layer2(const ushort* __restrict__ h1b,
                 const ushort* __restrict__ W2hi,
                 const int* __restrict__ ptr, const int* __restrict__ idx,
                 const int* __restrict__ etype,
                 float* __restrict__ out)
{
    __shared__ ushort aggHi[kNT][kLds];
    __shared__ __align__(16) char msgs[8 * 4096];
    __shared__ float logits[kNT][48];
    const int tid  = threadIdx.x;
    const int base = blockIdx.x * kNT;

    phaseA_mfma<0>(h1b, ptr, idx, etype, base, aggHi, msgs);
    __syncthreads();

    const int lane = tid & 63;
    const int wid  = tid >> 6;
    const int m    = lane & 15;
    const int q    = lane >> 4;

    if (wid < 3) {
        const bf16x8* Bh = (const bf16x8*)W2hi + (size_t)wid * 32 * 64 + lane;
        f32x4 acc = {0.f, 0.f, 0.f, 0.f};
        #pragma unroll 4
        for (int kt = 0; kt < 32; ++kt) {
            const bf16x8 ah = *(const bf16x8*)&aggHi[m][kt * 32 + q * 8];
            const bf16x8 bh = Bh[(size_t)kt * 64];
            acc = __builtin_amdgcn_mfma_f32_16x16x32_bf16(ah, bh, acc, 0, 0, 0);
        }
        const int n = wid * 16 + m;
        if (n < kOut) {
            #pragma unroll
            for (int i = 0; i < 4; ++i) {
                const int node = base + q * 4 + i;
                const float invdeg = 1.0f / (float)(ptr[node + 1] - ptr[node]);
                logits[q * 4 + i][n] = acc[i] * invdeg;
            }
        }
    }
    __syncthreads();

    #pragma unroll
    for (int i = 0; i < 2; ++i) {
        const int nrow = wid * 2 + i;
        const int node = base + nrow;
        const float v = (lane < kOut) ? logits[nrow][lane] : -INFINITY;
        float mx = v;
        #pragma unroll
        for (int off = 32; off > 0; off >>= 1)
            mx = fmaxf(mx, __shfl_xor(mx, off, 64));
        float s = (lane < kOut) ? __expf(v - mx) : 0.f;
        #pragma unroll
        for (int off = 32; off > 0; off >>= 1)
            s += __shfl_xor(s, off, 64);
        if (lane < kOut)
            out[(size_t)node * kOut + lane] = v - mx - __logf(s);
    }
}

// ---------------------------------------------------------------------------
// Layer 2z (R13 form): 16-lane group per node; 1 uint load per lane covers
// a full 64B edge slice per group -> 4 edges per wave-instruction.
// ---------------------------------------------------------------------------
__global__ __launch_bounds__(256)
void rgcn_layer2z(const uchar* __restrict__ z8,
                  const int* __restrict__ ptr, const int* __restrict__ idx,
                  const int* __restrict__ etype,
                  float* __restrict__ out)
{
    const int lane = threadIdx.x & 63;
    const int wv   = threadIdx.x >> 6;            // 4 waves/block
    const int n0   = blockIdx.x * 16 + wv * 4;    // wave covers nodes n0..n0+3
    const int g    = lane >> 4;                   // 16-lane group = local node
    const int c4   = (lane & 15) * 4;             // col base (4 cols per lane)
    const int node = n0 + g;

    const int p0 = ptr[n0];
    const int d0 = ptr[n0 + 1] - p0;
    const int d1 = ptr[n0 + 2] - ptr[n0 + 1];
    const int d2 = ptr[n0 + 3] - ptr[n0 + 2];
    const int d3 = ptr[n0 + 4] - ptr[n0 + 3];
    const bool fast = (d0 == 16) & (d1 == 16) & (d2 == 16) & (d3 == 16);

    float a0 = 0.f, a1 = 0.f, a2 = 0.f, a3 = 0.f;
    float invdeg;

    if (fast) {
        invdeg = 0.0625f;
        const int vi = idx  [p0 + lane];          // 64 edges, lane = edge slot
        const int ve = etype[p0 + lane];
        #pragma unroll
        for (int j = 0; j < 16; ++j) {
            const int E = g * 16 + j;             // this group's j-th edge
            const int s = __shfl(vi, E, 64);
            const int r = __shfl(ve, E, 64);
            const uint off = (uint)s * 512u + ((uint)r << 6) + (uint)c4;
            const uint v = *(const uint*)(z8 + off);
            a0 += fp82f((uchar)(v));
            a1 += fp82f((uchar)(v >> 8));
            a2 += fp82f((uchar)(v >> 16));
            a3 += fp82f((uchar)(v >> 24));
        }
    } else {                                      // generic (never hit)
        const int pa = ptr[node], pb = ptr[node + 1];
        invdeg = 1.0f / (float)(pb - pa);
        for (int e = pa; e < pb; ++e) {
            const int s = idx[e];
            const int r = etype[e];
            const uint off = (uint)s * 512u + ((uint)r << 6) + (uint)c4;
            const uint v = *(const uint*)(z8 + off);
            a0 += fp82f((uchar)(v));
            a1 += fp82f((uchar)(v >> 8));
            a2 += fp82f((uchar)(v >> 16));
            a3 += fp82f((uchar)(v >> 24));
        }
    }

    // softmax within the 16-lane group (lane&15 covers cols c4..c4+3)
    const bool valid = (lane & 15) < 10;          // c4+3 < 40
    const float v0 = a0 * invdeg, v1 = a1 * invdeg;
    const float v2 = a2 * invdeg, v3 = a3 * invdeg;
    float mx = valid ? fmaxf(fmaxf(v0, v1), fmaxf(v2, v3)) : -INFINITY;
    #pragma unroll
    for (int off = 8; off > 0; off >>= 1)
        mx = fmaxf(mx, __shfl_xor(mx, off, 64));
    float sm = valid ? (__expf(v0 - mx) + __expf(v1 - mx) +
                        __expf(v2 - mx) + __expf(v3 - mx)) : 0.f;
    #pragma unroll
    for (int off = 8; off > 0; off >>= 1)
        sm += __shfl_xor(sm, off, 64);
    if (valid) {
        const float lg = mx + __logf(sm);
        const float4 o4 = make_float4(v0 - lg, v1 - lg, v2 - lg, v3 - lg);
        *(float4*)&out[(size_t)node * kOut + c4] = o4;
    }
}

// ---------------------------------------------------------------------------
extern "C" void kernel_launch(void* const* d_in, const int* in_sizes, int n_in,
                              void* d_out, int out_size, void* d_ws, size_t ws_size,
                              hipStream_t stream)
{
    const float* x     = (const float*)d_in[0];
    const float* W1    = (const float*)d_in[1];
    const float* W2    = (const float*)d_in[2];
    const float* gamma = (const float*)d_in[3];
    const float* beta  = (const float*)d_in[4];
    const float* mean  = (const float*)d_in[5];
    const float* var   = (const float*)d_in[6];
    const int*   ptr   = (const int*)d_in[7];
    const int*   idx   = (const int*)d_in[8];
    const int*   et    = (const int*)d_in[9];
    float*       out   = (float*)d_out;

    char* ws = (char*)d_ws;
    ushort* W1hi = (ushort*)ws;
    ushort* W2hi = (ushort*)(ws + kOffW2hi);
    ushort* W2z  = (ushort*)(ws + kOffW2z);
    ushort* xb   = (ushort*)(ws + kOffXb);       // bf16 (fallback) or fp8 (useZ)
    ushort* h1b  = (ushort*)(ws + kOffBig);      // fallback only
    uchar*  z8   = (uchar*)(ws + kOffBig);       // useZ path

    const int useZ = (ws_size >= kOffBig + kZBytes) ? 1 : 0;

    prep<<<dim3(3245), dim3(256), 0, stream>>>(x, xb, W1, W1hi, W2, W2hi,
                                               W2z, useZ);

    dim3 grid(kN / kNT), block(512);
    rgcn_layer1<<<grid, block, 0, stream>>>(xb, W1hi, W2z, gamma, beta, mean,
                                            var, ptr, idx, et, h1b, z8, useZ);
    if (useZ) {
        rgcn_layer2z<<<dim3(kN / 16), dim3(256), 0, stream>>>(z8, ptr, idx,
                                                              et, out);
    } else {
        rgcn_layer2<<<grid, block, 0, stream>>>(h1b, W2hi, ptr, idx, et, out);
    }
}